// Round 1
// baseline (3258.955 us; speedup 1.0000x reference)
//
#include <hip/hip_runtime.h>

__device__ __forceinline__ float relu(float v) { return v > 0.f ? v : 0.f; }

// ---------- transpose: out[k*R + c] = in[c*stride + k], k < C (C = 2^logC), c < R
__global__ void ktr(const float* __restrict__ in, float* __restrict__ out,
                    int R, int logC, int stride) {
  int idx = blockIdx.x * 256 + threadIdx.x;
  int C = 1 << logC;
  if (idx >= R * C) return;
  int k = idx & (C - 1);
  int c = idx >> logC;
  out[(size_t)k * R + c] = in[(size_t)c * stride + k];
}

// ---------- k1: h2 = relu(relu(x@W1.T+b1)@W2.T+b2), thread-per-point
__global__ __launch_bounds__(256) void k1(
    const float* __restrict__ x, const float* __restrict__ W1, const float* __restrict__ b1,
    const float* __restrict__ W2, const float* __restrict__ b2, float* __restrict__ h2g) {
  int p = blockIdx.x * 256 + threadIdx.x;
  float x0 = x[p * 3 + 0], x1 = x[p * 3 + 1], x2 = x[p * 3 + 2];
  float h1[64];
#pragma unroll
  for (int c = 0; c < 64; ++c)
    h1[c] = relu(W1[c * 3 + 0] * x0 + W1[c * 3 + 1] * x1 + W1[c * 3 + 2] * x2 + b1[c]);
  float4* outp = (float4*)(h2g + (size_t)p * 64);
  for (int c = 0; c < 64; c += 4) {
    float a0 = b2[c], a1 = b2[c + 1], a2 = b2[c + 2], a3 = b2[c + 3];
#pragma unroll
    for (int k = 0; k < 64; ++k) {
      float hv = h1[k];
      a0 += hv * W2[(c + 0) * 64 + k];
      a1 += hv * W2[(c + 1) * 64 + k];
      a2 += hv * W2[(c + 2) * 64 + k];
      a3 += hv * W2[(c + 3) * 64 + k];
    }
    outp[c >> 2] = make_float4(relu(a0), relu(a1), relu(a2), relu(a3));
  }
}

// ---------- k2: y3 = relu(h2@W3.T+b3); y4 = relu(y3@W4.T+b4); g = max over points
// grid (256 point-blocks, 4 channel-quarters); thread-per-point, y3 in VGPRs,
// W3/W4 reads are wave-uniform -> scalar loads.
__global__ __launch_bounds__(256) void k2(
    const float* __restrict__ h2g, const float* __restrict__ W3, const float* __restrict__ b3,
    const float* __restrict__ W4, const float* __restrict__ b4, float* __restrict__ g) {
  __shared__ float swmax[4][256];
  int tid = threadIdx.x;
  int p = blockIdx.x * 256 + tid;
  int lane = tid & 63, w = tid >> 6;
  int cbase = blockIdx.y * 256;

  float h[64];
  const float4* hp = (const float4*)(h2g + (size_t)p * 64);
#pragma unroll
  for (int i = 0; i < 16; ++i) {
    float4 v = hp[i];
    h[4 * i + 0] = v.x; h[4 * i + 1] = v.y; h[4 * i + 2] = v.z; h[4 * i + 3] = v.w;
  }

  float y3[128];
#pragma unroll
  for (int c = 0; c < 128; c += 4) {
    float a0 = b3[c], a1 = b3[c + 1], a2 = b3[c + 2], a3 = b3[c + 3];
#pragma unroll
    for (int k = 0; k < 64; ++k) {
      float hv = h[k];
      a0 += hv * W3[(c + 0) * 64 + k];
      a1 += hv * W3[(c + 1) * 64 + k];
      a2 += hv * W3[(c + 2) * 64 + k];
      a3 += hv * W3[(c + 3) * 64 + k];
    }
    y3[c] = relu(a0); y3[c + 1] = relu(a1); y3[c + 2] = relu(a2); y3[c + 3] = relu(a3);
  }

  for (int c = cbase; c < cbase + 256; c += 2) {
    float a0 = b4[c], a1 = b4[c + 1];
#pragma unroll
    for (int k = 0; k < 128; ++k) {
      a0 += y3[k] * W4[(size_t)c * 128 + k];
      a1 += y3[k] * W4[(size_t)(c + 1) * 128 + k];
    }
    a0 = relu(a0); a1 = relu(a1);
#pragma unroll
    for (int off = 32; off >= 1; off >>= 1) {
      a0 = fmaxf(a0, __shfl_xor(a0, off));
      a1 = fmaxf(a1, __shfl_xor(a1, off));
    }
    if (lane == 0) { swmax[w][c - cbase] = a0; swmax[w][c - cbase + 1] = a1; }
  }
  __syncthreads();
  {
    float m = fmaxf(fmaxf(swmax[0][tid], swmax[1][tid]), fmaxf(swmax[2][tid], swmax[3][tid]));
    atomicMax((unsigned int*)(g + cbase + tid), __float_as_uint(m));
  }
}

// ---------- kc5: c5[c] = sum_k W5[c][64+k] * g[k] + b5[c]
__global__ __launch_bounds__(256) void kc5(
    const float* __restrict__ W5, const float* __restrict__ b5,
    const float* __restrict__ g, float* __restrict__ c5) {
  int tid = threadIdx.x;
  int ci = tid >> 3, kg = tid & 7;
  int c = blockIdx.x * 32 + ci;
  const float* wrow = W5 + (size_t)c * 1088 + 64 + kg * 128;
  const float* gp = g + kg * 128;
  float acc = 0.f;
#pragma unroll 8
  for (int k = 0; k < 128; ++k) acc += wrow[k] * gp[k];
#pragma unroll
  for (int off = 1; off <= 4; off <<= 1) acc += __shfl_xor(acc, off);
  if (kg == 0) c5[c] = acc + b5[c];
}

// ---------- k4: z5=relu(h2@W5a.T + c5); z6=relu(z5@W6.T+b6); z7=relu(z6@W7.T+b7); out=z7@W8.T+b8
// 16 points per block; weights pre-transposed to [k][c]; activations in padded LDS.
__global__ __launch_bounds__(256) void k4(
    const float* __restrict__ h2g, const float* __restrict__ c5v,
    const float* __restrict__ W5T, const float* __restrict__ W6T, const float* __restrict__ b6,
    const float* __restrict__ W7T, const float* __restrict__ b7,
    const float* __restrict__ W8, const float* __restrict__ b8,
    float* __restrict__ out) {
  __shared__ float sh2[16][68];   // pad +4 floats: 16B-aligned rows, bank-shifted
  __shared__ float z5[16][516];
  __shared__ float z6[16][260];
  __shared__ float z7[16][132];
  int tid = threadIdx.x;
  int ci = tid & 31, pg = tid >> 5;   // 32 channel-lanes x 8 point-groups
  int p0 = pg * 2;                    // 2 points per thread
  int pbase = blockIdx.x * 16;

  {  // stage h2 tile, coalesced (1024 floats, one float4 per thread)
    int i = tid * 4;
    int p = i >> 6, k = i & 63;
    float4 v = *(const float4*)(h2g + (size_t)(pbase + p) * 64 + k);
    *(float4*)&sh2[p][k] = v;
  }
  __syncthreads();

  // ---- L5': 512 channels, K=64. c = ci*4 + 128*jg + jj
  {
    float acc[2][4][4];
#pragma unroll
    for (int jg = 0; jg < 4; ++jg) {
      float4 cc = *(const float4*)(c5v + ci * 4 + 128 * jg);
#pragma unroll
      for (int p = 0; p < 2; ++p) {
        acc[p][jg][0] = cc.x; acc[p][jg][1] = cc.y; acc[p][jg][2] = cc.z; acc[p][jg][3] = cc.w;
      }
    }
    for (int k = 0; k < 64; k += 4) {
      float4 a0 = *(const float4*)&sh2[p0][k];
      float4 a1 = *(const float4*)&sh2[p0 + 1][k];
      float av0[4] = {a0.x, a0.y, a0.z, a0.w};
      float av1[4] = {a1.x, a1.y, a1.z, a1.w};
#pragma unroll
      for (int kk = 0; kk < 4; ++kk) {
#pragma unroll
        for (int jg = 0; jg < 4; ++jg) {
          float4 wv = *(const float4*)(W5T + (size_t)(k + kk) * 512 + ci * 4 + 128 * jg);
          acc[0][jg][0] += av0[kk] * wv.x; acc[0][jg][1] += av0[kk] * wv.y;
          acc[0][jg][2] += av0[kk] * wv.z; acc[0][jg][3] += av0[kk] * wv.w;
          acc[1][jg][0] += av1[kk] * wv.x; acc[1][jg][1] += av1[kk] * wv.y;
          acc[1][jg][2] += av1[kk] * wv.z; acc[1][jg][3] += av1[kk] * wv.w;
        }
      }
    }
#pragma unroll
    for (int p = 0; p < 2; ++p)
#pragma unroll
      for (int jg = 0; jg < 4; ++jg)
        *(float4*)&z5[p0 + p][ci * 4 + 128 * jg] =
            make_float4(relu(acc[p][jg][0]), relu(acc[p][jg][1]),
                        relu(acc[p][jg][2]), relu(acc[p][jg][3]));
  }
  __syncthreads();

  // ---- L6: 256 channels, K=512
  {
    float acc[2][2][4];
#pragma unroll
    for (int jg = 0; jg < 2; ++jg) {
      float4 bb = *(const float4*)(b6 + ci * 4 + 128 * jg);
#pragma unroll
      for (int p = 0; p < 2; ++p) {
        acc[p][jg][0] = bb.x; acc[p][jg][1] = bb.y; acc[p][jg][2] = bb.z; acc[p][jg][3] = bb.w;
      }
    }
    for (int k = 0; k < 512; k += 4) {
      float4 a0 = *(const float4*)&z5[p0][k];
      float4 a1 = *(const float4*)&z5[p0 + 1][k];
      float av0[4] = {a0.x, a0.y, a0.z, a0.w};
      float av1[4] = {a1.x, a1.y, a1.z, a1.w};
#pragma unroll
      for (int kk = 0; kk < 4; ++kk) {
#pragma unroll
        for (int jg = 0; jg < 2; ++jg) {
          float4 wv = *(const float4*)(W6T + (size_t)(k + kk) * 256 + ci * 4 + 128 * jg);
          acc[0][jg][0] += av0[kk] * wv.x; acc[0][jg][1] += av0[kk] * wv.y;
          acc[0][jg][2] += av0[kk] * wv.z; acc[0][jg][3] += av0[kk] * wv.w;
          acc[1][jg][0] += av1[kk] * wv.x; acc[1][jg][1] += av1[kk] * wv.y;
          acc[1][jg][2] += av1[kk] * wv.z; acc[1][jg][3] += av1[kk] * wv.w;
        }
      }
    }
#pragma unroll
    for (int p = 0; p < 2; ++p)
#pragma unroll
      for (int jg = 0; jg < 2; ++jg)
        *(float4*)&z6[p0 + p][ci * 4 + 128 * jg] =
            make_float4(relu(acc[p][jg][0]), relu(acc[p][jg][1]),
                        relu(acc[p][jg][2]), relu(acc[p][jg][3]));
  }
  __syncthreads();

  // ---- L7: 128 channels, K=256
  {
    float acc[2][4];
    float4 bb = *(const float4*)(b7 + ci * 4);
#pragma unroll
    for (int p = 0; p < 2; ++p) {
      acc[p][0] = bb.x; acc[p][1] = bb.y; acc[p][2] = bb.z; acc[p][3] = bb.w;
    }
    for (int k = 0; k < 256; k += 4) {
      float4 a0 = *(const float4*)&z6[p0][k];
      float4 a1 = *(const float4*)&z6[p0 + 1][k];
      float av0[4] = {a0.x, a0.y, a0.z, a0.w};
      float av1[4] = {a1.x, a1.y, a1.z, a1.w};
#pragma unroll
      for (int kk = 0; kk < 4; ++kk) {
        float4 wv = *(const float4*)(W7T + (size_t)(k + kk) * 128 + ci * 4);
        acc[0][0] += av0[kk] * wv.x; acc[0][1] += av0[kk] * wv.y;
        acc[0][2] += av0[kk] * wv.z; acc[0][3] += av0[kk] * wv.w;
        acc[1][0] += av1[kk] * wv.x; acc[1][1] += av1[kk] * wv.y;
        acc[1][2] += av1[kk] * wv.z; acc[1][3] += av1[kk] * wv.w;
      }
    }
#pragma unroll
    for (int p = 0; p < 2; ++p)
      *(float4*)&z7[p0 + p][ci * 4] =
          make_float4(relu(acc[p][0]), relu(acc[p][1]), relu(acc[p][2]), relu(acc[p][3]));
  }
  __syncthreads();

  // ---- L8: 1 channel, K=128, no relu
  if (tid < 16) {
    float acc = b8[0];
#pragma unroll
    for (int k = 0; k < 128; ++k) acc += z7[tid][k] * W8[k];
    out[pbase + tid] = acc;
  }
}

extern "C" void kernel_launch(void* const* d_in, const int* in_sizes, int n_in,
                              void* d_out, int out_size, void* d_ws, size_t ws_size,
                              hipStream_t stream) {
  const float* x  = (const float*)d_in[0];
  const float* W1 = (const float*)d_in[1];  const float* b1 = (const float*)d_in[2];
  const float* W2 = (const float*)d_in[3];  const float* b2 = (const float*)d_in[4];
  const float* W3 = (const float*)d_in[5];  const float* b3 = (const float*)d_in[6];
  const float* W4 = (const float*)d_in[7];  const float* b4 = (const float*)d_in[8];
  const float* W5 = (const float*)d_in[9];  const float* b5 = (const float*)d_in[10];
  const float* W6 = (const float*)d_in[11]; const float* b6 = (const float*)d_in[12];
  const float* W7 = (const float*)d_in[13]; const float* b7 = (const float*)d_in[14];
  const float* W8 = (const float*)d_in[15]; const float* b8 = (const float*)d_in[16];
  float* out = (float*)d_out;

  char* ws = (char*)d_ws;
  float* h2g = (float*)(ws);                                  // 16 MB: [65536][64]
  float* g   = (float*)(ws + (16u << 20));                    // 4 KB
  float* c5  = (float*)(ws + (16u << 20) + 4096);             // 2 KB
  float* W5T = (float*)(ws + (16u << 20) + 4096 + 2048);                      // 128 KB [64][512]
  float* W6T = (float*)(ws + (16u << 20) + 4096 + 2048 + 131072);             // 512 KB [512][256]
  float* W7T = (float*)(ws + (16u << 20) + 4096 + 2048 + 131072 + 524288);    // 128 KB [256][128]

  hipMemsetAsync(g, 0, 1024 * sizeof(float), stream);  // relu outputs >= 0, so 0 is a valid max identity
  ktr<<<(512 * 64) / 256, 256, 0, stream>>>(W5, W5T, 512, 6, 1088);
  ktr<<<(256 * 512) / 256, 256, 0, stream>>>(W6, W6T, 256, 9, 512);
  ktr<<<(128 * 256) / 256, 256, 0, stream>>>(W7, W7T, 128, 8, 256);
  k1<<<256, 256, 0, stream>>>(x, W1, b1, W2, b2, h2g);
  k2<<<dim3(256, 4), 256, 0, stream>>>(h2g, W3, b3, W4, b4, g);
  kc5<<<16, 256, 0, stream>>>(W5, b5, g, c5);
  k4<<<4096, 256, 0, stream>>>(h2g, c5, W5T, W6T, b6, W7T, b7, W8, b8, out);
}

// Round 2
// 3028.098 us; speedup vs baseline: 1.0762x; 1.0762x over previous
//
#include <hip/hip_runtime.h>

#define NPTS 65536

__device__ __forceinline__ float relu(float v) { return v > 0.f ? v : 0.f; }

// ============ k1: h2T[c][p] = relu(relu(x@W1.T+b1)@W2.T+b2)  (c-quarters on blockIdx.y)
__global__ __launch_bounds__(256, 4) void k1(
    const float* __restrict__ x, const float* __restrict__ W1, const float* __restrict__ b1,
    const float* __restrict__ W2, const float* __restrict__ b2, float* __restrict__ h2T) {
  int p = blockIdx.x * 256 + threadIdx.x;
  float x0 = x[p * 3 + 0], x1 = x[p * 3 + 1], x2 = x[p * 3 + 2];
  float h1[64];
#pragma unroll
  for (int c = 0; c < 64; ++c)
    h1[c] = relu(fmaf(W1[c * 3 + 0], x0, fmaf(W1[c * 3 + 1], x1, fmaf(W1[c * 3 + 2], x2, b1[c]))));
  int cq = blockIdx.y * 16;  // 16 channels per block.y quarter
  for (int c0 = cq; c0 < cq + 16; c0 += 8) {
    float acc[8];
#pragma unroll
    for (int cc = 0; cc < 8; ++cc) acc[cc] = b2[c0 + cc];
#pragma unroll
    for (int k = 0; k < 64; ++k) {
      float av = h1[k];
#pragma unroll
      for (int cc = 0; cc < 8; ++cc) acc[cc] = fmaf(av, W2[(c0 + cc) * 64 + k], acc[cc]);
    }
#pragma unroll
    for (int cc = 0; cc < 8; ++cc) h2T[(size_t)(c0 + cc) * NPTS + p] = relu(acc[cc]);
  }
}

// ============ kL3: y3T[c][p] = relu(h2 @ W3.T + b3)   K=64, N=128, c-quarters of 32
__global__ __launch_bounds__(256, 4) void kL3(
    const float* __restrict__ h2T, const float* __restrict__ W3, const float* __restrict__ b3,
    float* __restrict__ y3T) {
  int p = blockIdx.x * 256 + threadIdx.x;
  float a[64];
#pragma unroll
  for (int k = 0; k < 64; ++k) a[k] = h2T[(size_t)k * NPTS + p];
  int cq = blockIdx.y * 32;
  for (int c0 = cq; c0 < cq + 32; c0 += 8) {
    float acc[8];
#pragma unroll
    for (int cc = 0; cc < 8; ++cc) acc[cc] = b3[c0 + cc];
#pragma unroll
    for (int k = 0; k < 64; ++k) {
      float av = a[k];
#pragma unroll
      for (int cc = 0; cc < 8; ++cc) acc[cc] = fmaf(av, W3[(c0 + cc) * 64 + k], acc[cc]);
    }
#pragma unroll
    for (int cc = 0; cc < 8; ++cc) y3T[(size_t)(c0 + cc) * NPTS + p] = relu(acc[cc]);
  }
}

// ============ kL4: y4 = relu(y3@W4.T+b4); per-wave column-max -> gpart (no y4 materialization)
// grid (256 point-blocks, 4 channel-quarters of 256). gpart[(q*1024 + row)][0..255]
__global__ __launch_bounds__(256, 2) void kL4(
    const float* __restrict__ y3T, const float* __restrict__ W4, const float* __restrict__ b4,
    float* __restrict__ gpart) {
  int tid = threadIdx.x;
  int p = blockIdx.x * 256 + tid;
  int lane = tid & 63, w = tid >> 6;
  int q = blockIdx.y;
  int row = blockIdx.x * 4 + w;
  float a[128];
#pragma unroll
  for (int k = 0; k < 128; ++k) a[k] = y3T[(size_t)k * NPTS + p];
  for (int c0l = 0; c0l < 256; c0l += 8) {
    int c0 = q * 256 + c0l;
    float acc[8];
#pragma unroll
    for (int cc = 0; cc < 8; ++cc) acc[cc] = b4[c0 + cc];
#pragma unroll
    for (int k = 0; k < 128; ++k) {
      float av = a[k];
#pragma unroll
      for (int cc = 0; cc < 8; ++cc) acc[cc] = fmaf(av, W4[(size_t)(c0 + cc) * 128 + k], acc[cc]);
    }
#pragma unroll
    for (int cc = 0; cc < 8; ++cc) {
      float v = relu(acc[cc]);
#pragma unroll
      for (int off = 32; off >= 1; off >>= 1) v = fmaxf(v, __shfl_xor(v, off));
      if (lane == 0) gpart[(size_t)(q * 1024 + row) * 256 + c0l + cc] = v;
    }
  }
}

// ============ kgmax: g[c] = max over 1024 rows of gpart (16 row-chunks x 1024 c = 16384 threads)
__global__ __launch_bounds__(256) void kgmax(const float* __restrict__ gpart, float* __restrict__ g) {
  int t = blockIdx.x * 256 + threadIdx.x;
  int c = t & 1023, rchunk = t >> 10;
  int q = c >> 8, col = c & 255;
  const float* gp = gpart + (size_t)(q * 1024 + rchunk * 64) * 256 + col;
  float m = 0.f;
#pragma unroll 8
  for (int r = 0; r < 64; ++r) m = fmaxf(m, gp[(size_t)r * 256]);
  atomicMax((unsigned int*)(g + c), __float_as_uint(m));  // all values >= 0
}

// ============ kc5: c5[c] = W5[c][64:1088] @ g + b5[c]
__global__ __launch_bounds__(256) void kc5(
    const float* __restrict__ W5, const float* __restrict__ b5,
    const float* __restrict__ g, float* __restrict__ c5) {
  int tid = threadIdx.x;
  int ci = tid >> 3, kg = tid & 7;
  int c = blockIdx.x * 32 + ci;
  const float* wrow = W5 + (size_t)c * 1088 + 64 + kg * 128;
  const float* gp = g + kg * 128;
  float acc = 0.f;
#pragma unroll 8
  for (int k = 0; k < 128; ++k) acc += wrow[k] * gp[k];
#pragma unroll
  for (int off = 1; off <= 4; off <<= 1) acc += __shfl_xor(acc, off);
  if (kg == 0) c5[c] = acc + b5[c];
}

// ============ kL5: z5T[c][p] = relu(h2 @ W5[:, :64].T + c5)  K=64, N=512, c-quarters of 128
__global__ __launch_bounds__(256, 4) void kL5(
    const float* __restrict__ h2T, const float* __restrict__ W5, const float* __restrict__ c5v,
    float* __restrict__ z5T) {
  int p = blockIdx.x * 256 + threadIdx.x;
  float a[64];
#pragma unroll
  for (int k = 0; k < 64; ++k) a[k] = h2T[(size_t)k * NPTS + p];
  int cq = blockIdx.y * 128;
  for (int c0 = cq; c0 < cq + 128; c0 += 8) {
    float acc[8];
#pragma unroll
    for (int cc = 0; cc < 8; ++cc) acc[cc] = c5v[c0 + cc];
#pragma unroll
    for (int k = 0; k < 64; ++k) {
      float av = a[k];
#pragma unroll
      for (int cc = 0; cc < 8; ++cc) acc[cc] = fmaf(av, W5[(size_t)(c0 + cc) * 1088 + k], acc[cc]);
    }
#pragma unroll
    for (int cc = 0; cc < 8; ++cc) z5T[(size_t)(c0 + cc) * NPTS + p] = relu(acc[cc]);
  }
}

// ============ kL6: z6T = relu(z5 @ W6.T + b6)  K=512 split over 4 waves (128 each), 64 pts/block
__global__ __launch_bounds__(256, 2) void kL6(
    const float* __restrict__ z5T, const float* __restrict__ W6, const float* __restrict__ b6,
    float* __restrict__ z6T) {
  __shared__ float part[4][8][64];
  int tid = threadIdx.x;
  int lane = tid & 63;
  int w = __builtin_amdgcn_readfirstlane(tid >> 6);  // force wave-uniform SGPR
  int p = blockIdx.x * 64 + lane;
  float a[128];
#pragma unroll
  for (int j = 0; j < 128; ++j) a[j] = z5T[(size_t)(w * 128 + j) * NPTS + p];
  for (int c0 = 0; c0 < 256; c0 += 8) {
    float acc[8];
#pragma unroll
    for (int cc = 0; cc < 8; ++cc) acc[cc] = 0.f;
#pragma unroll
    for (int k = 0; k < 128; ++k) {
      float av = a[k];
#pragma unroll
      for (int cc = 0; cc < 8; ++cc)
        acc[cc] = fmaf(av, W6[(size_t)(c0 + cc) * 512 + w * 128 + k], acc[cc]);
    }
#pragma unroll
    for (int cc = 0; cc < 8; ++cc) part[w][cc][lane] = acc[cc];
    __syncthreads();
#pragma unroll
    for (int r = 0; r < 2; ++r) {
      int cc = w * 2 + r;
      float v = part[0][cc][lane] + part[1][cc][lane] + part[2][cc][lane] + part[3][cc][lane]
                + b6[c0 + cc];
      z6T[(size_t)(c0 + cc) * NPTS + p] = relu(v);
    }
    __syncthreads();
  }
}

// ============ kL7: z7T = relu(z6 @ W7.T + b7)  K=256 split over 4 waves (64 each), 64 pts/block
__global__ __launch_bounds__(256, 4) void kL7(
    const float* __restrict__ z6T, const float* __restrict__ W7, const float* __restrict__ b7,
    float* __restrict__ z7T) {
  __shared__ float part[4][8][64];
  int tid = threadIdx.x;
  int lane = tid & 63;
  int w = __builtin_amdgcn_readfirstlane(tid >> 6);
  int p = blockIdx.x * 64 + lane;
  float a[64];
#pragma unroll
  for (int j = 0; j < 64; ++j) a[j] = z6T[(size_t)(w * 64 + j) * NPTS + p];
  for (int c0 = 0; c0 < 128; c0 += 8) {
    float acc[8];
#pragma unroll
    for (int cc = 0; cc < 8; ++cc) acc[cc] = 0.f;
#pragma unroll
    for (int k = 0; k < 64; ++k) {
      float av = a[k];
#pragma unroll
      for (int cc = 0; cc < 8; ++cc)
        acc[cc] = fmaf(av, W7[(size_t)(c0 + cc) * 256 + w * 64 + k], acc[cc]);
    }
#pragma unroll
    for (int cc = 0; cc < 8; ++cc) part[w][cc][lane] = acc[cc];
    __syncthreads();
#pragma unroll
    for (int r = 0; r < 2; ++r) {
      int cc = w * 2 + r;
      float v = part[0][cc][lane] + part[1][cc][lane] + part[2][cc][lane] + part[3][cc][lane]
                + b7[c0 + cc];
      z7T[(size_t)(c0 + cc) * NPTS + p] = relu(v);
    }
    __syncthreads();
  }
}

// ============ kL8: out[p] = z7[p] @ W8 + b8   K=128 split over 4 waves (32 each), 64 pts/block
__global__ __launch_bounds__(256) void kL8(
    const float* __restrict__ z7T, const float* __restrict__ W8, const float* __restrict__ b8,
    float* __restrict__ out) {
  __shared__ float part[4][64];
  int tid = threadIdx.x;
  int lane = tid & 63;
  int w = __builtin_amdgcn_readfirstlane(tid >> 6);
  int p = blockIdx.x * 64 + lane;
  float acc = 0.f;
#pragma unroll
  for (int j = 0; j < 32; ++j)
    acc = fmaf(z7T[(size_t)(w * 32 + j) * NPTS + p], W8[w * 32 + j], acc);
  part[w][lane] = acc;
  __syncthreads();
  if (tid < 64)
    out[blockIdx.x * 64 + tid] =
        part[0][tid] + part[1][tid] + part[2][tid] + part[3][tid] + b8[0];
}

extern "C" void kernel_launch(void* const* d_in, const int* in_sizes, int n_in,
                              void* d_out, int out_size, void* d_ws, size_t ws_size,
                              hipStream_t stream) {
  const float* x  = (const float*)d_in[0];
  const float* W1 = (const float*)d_in[1];  const float* b1 = (const float*)d_in[2];
  const float* W2 = (const float*)d_in[3];  const float* b2 = (const float*)d_in[4];
  const float* W3 = (const float*)d_in[5];  const float* b3 = (const float*)d_in[6];
  const float* W4 = (const float*)d_in[7];  const float* b4 = (const float*)d_in[8];
  const float* W5 = (const float*)d_in[9];  const float* b5 = (const float*)d_in[10];
  const float* W6 = (const float*)d_in[11]; const float* b6 = (const float*)d_in[12];
  const float* W7 = (const float*)d_in[13]; const float* b7 = (const float*)d_in[14];
  const float* W8 = (const float*)d_in[15]; const float* b8 = (const float*)d_in[16];
  float* out = (float*)d_out;

  // Workspace layout (overlays exploit lifetimes; ~208 MB total):
  //   z5T  [0,128M)        live kL5 -> kL6
  //   h2T  [128M,144M)     live k1  -> kL5
  //   y3T  [144M,176M)     live kL3 -> kL4   (overlaid by z6T later)
  //   gpart[176M,180M)     live kL4 -> kgmax (overlaid by z6T later)
  //   z6T  [144M,208M)     live kL6 -> kL7   (over y3T+gpart, both dead)
  //   z7T  [0,32M)         live kL7 -> kL8   (over z5T, dead after kL6)
  //   g    [208M, +4K), c5 [208M+4K, +2K)
  char* ws = (char*)d_ws;
  float* z5T   = (float*)(ws);
  float* h2T   = (float*)(ws + 134217728ULL);
  float* y3T   = (float*)(ws + 150994944ULL);
  float* gpart = (float*)(ws + 184549376ULL);
  float* z6T   = (float*)(ws + 150994944ULL);
  float* z7T   = (float*)(ws);
  float* g     = (float*)(ws + 218103808ULL);
  float* c5    = (float*)(ws + 218103808ULL + 4096);

  hipMemsetAsync(g, 0, 1024 * sizeof(float), stream);  // max identity (relu outputs >= 0)
  k1   <<<dim3(256, 4), 256, 0, stream>>>(x, W1, b1, W2, b2, h2T);
  kL3  <<<dim3(256, 4), 256, 0, stream>>>(h2T, W3, b3, y3T);
  kL4  <<<dim3(256, 4), 256, 0, stream>>>(y3T, W4, b4, gpart);
  kgmax<<<64, 256, 0, stream>>>(gpart, g);
  kc5  <<<16, 256, 0, stream>>>(W5, b5, g, c5);
  kL5  <<<dim3(256, 4), 256, 0, stream>>>(h2T, W5, c5, z5T);
  kL6  <<<1024, 256, 0, stream>>>(z5T, W6, b6, z6T);
  kL7  <<<1024, 256, 0, stream>>>(z6T, W7, b7, z7T);
  kL8  <<<1024, 256, 0, stream>>>(z7T, W8, b8, out);
}